// Round 1
// baseline (70.180 us; speedup 1.0000x reference)
//
#include <hip/hip_runtime.h>

// Correlation layer, specialized: s1=2, s2=1, d=4  ->  integer even sampling,
// bilinear weights are exactly 0 -> pure gather of v00.
// out[b, j*9+i, h1, w1] = (1/256) * sum_c x1[b,c,2h1,2w1] * x2[b,c,2(h1+j-4),2(w1+i-4)]
// (zero when displaced position is out of the 24x24 downsampled grid)

constexpr int NB = 16, NC = 256, NH = 48, NW = 48;
constexpr int H1 = 24, W1 = 24;       // downsampled grid
constexpr int NK = 81;                // 9x9 displacements
constexpr int CSPLIT = 4;             // channel split across blocks
constexpr int CPB = NC / CSPLIT;      // 64 channels per block
constexpr int CCHUNK = 32;            // channels per LDS stage
constexpr int TH = 4;                 // h1 rows per block
constexpr int TWH = 12;               // w1 cols per block
constexpr int OUTSZ = NB * NK * H1 * W1;  // 746496

// MODE 0: write per-csplit partials to ws (deterministic, reduce kernel sums)
// MODE 1: atomicAdd directly into d_out (fallback if ws too small)
template<int MODE>
__global__ __launch_bounds__(128) void corr_main(
    const float* __restrict__ x1, const float* __restrict__ x2,
    float* __restrict__ dst)
{
  const int t = threadIdx.x;
  const int h1t   = blockIdx.x >> 1;
  const int whalf = blockIdx.x & 1;
  const int b  = blockIdx.y;
  const int cz = blockIdx.z;
  const int h1base = h1t * TH;
  const int wbase  = whalf * TWH;

  __shared__ float s1[CCHUNK][TH][TWH];     // x1s tile (even rows/cols of x1)
  __shared__ float s2[CCHUNK][TH + 8][28];  // x2s tile: 20 data cols, stride 28 (bank spread)

  // compute-thread decomposition: (h1l, j, wg) ; 4*9*3 = 108 active of 128
  const int h1l = t / 27;
  const int rr  = t % 27;
  const int j   = rr / 3;     // y-displacement index (dy = j-4 on the 24x24 grid)
  const int wg  = rr % 3;     // w1 group of 4
  const bool active = (t < 108);

  float acc[9][4];
  #pragma unroll
  for (int i = 0; i < 9; ++i)
    #pragma unroll
    for (int w = 0; w < 4; ++w) acc[i][w] = 0.f;

  for (int ch = 0; ch < CPB; ch += CCHUNK) {
    const int cb = cz * CPB + ch;
    __syncthreads();  // protect LDS from previous iteration's readers
    // stage x1s tile: 32c * 4h * 12w = 1536 elements (stride-2 global reads)
    for (int idx = t; idx < CCHUNK * TH * TWH; idx += 128) {
      const int wl = idx % TWH;
      const int hh = (idx / TWH) % TH;
      const int cc = idx / (TWH * TH);
      s1[cc][hh][wl] =
          x1[(((b * NC + cb + cc) * NH + 2 * (h1base + hh)) * NW) + 2 * (wbase + wl)];
    }
    // stage x2s window: 32c * 12rows * 20cols = 7680 elements, zero-padded OOB
    for (int idx = t; idx < CCHUNK * 12 * 20; idx += 128) {
      const int xl = idx % 20;
      const int r  = (idx / 20) % 12;
      const int cc = idx / (20 * 12);
      const int ys = h1base - 4 + r;       // downsampled row
      const int xs = wbase - 4 + xl;       // downsampled col
      float v = 0.f;
      if (ys >= 0 && ys < H1 && xs >= 0 && xs < W1)
        v = x2[(((b * NC + cb + cc) * NH + 2 * ys) * NW) + 2 * xs];
      s2[cc][r][xl] = v;
    }
    __syncthreads();
    if (active) {
      #pragma unroll 4
      for (int cc = 0; cc < CCHUNK; ++cc) {
        const float4 a4 = *(const float4*)&s1[cc][h1l][wg * 4];
        const float* xr = &s2[cc][h1l + j][wg * 4];
        const float4 b0 = *(const float4*)&xr[0];
        const float4 b1 = *(const float4*)&xr[4];
        const float4 b2 = *(const float4*)&xr[8];
        const float av[4] = {a4.x, a4.y, a4.z, a4.w};
        const float xw[12] = {b0.x, b0.y, b0.z, b0.w, b1.x, b1.y, b1.z, b1.w,
                              b2.x, b2.y, b2.z, b2.w};
        #pragma unroll
        for (int i = 0; i < 9; ++i)
          #pragma unroll
          for (int w = 0; w < 4; ++w)
            acc[i][w] = fmaf(av[w], xw[w + i], acc[i][w]);
      }
    }
  }
  if (!active) return;
  const int h1 = h1base + h1l;
  const int w1 = wbase + wg * 4;
  if (MODE == 0) {
    float* base = dst + (size_t)cz * OUTSZ + (size_t)b * NK * (H1 * W1);
    #pragma unroll
    for (int i = 0; i < 9; ++i) {
      const int k = j * 9 + i;
      float4 v = make_float4(acc[i][0], acc[i][1], acc[i][2], acc[i][3]);
      *(float4*)&base[(k * H1 + h1) * W1 + w1] = v;
    }
  } else {
    #pragma unroll
    for (int i = 0; i < 9; ++i) {
      const int k = j * 9 + i;
      #pragma unroll
      for (int w = 0; w < 4; ++w)
        atomicAdd(&dst[((size_t)(b * NK + k) * H1 + h1) * W1 + w1 + w],
                  acc[i][w] * (1.f / 256.f));
    }
  }
}

__global__ __launch_bounds__(256) void corr_reduce(const float* __restrict__ part,
                                                   float* __restrict__ out)
{
  const int n4 = OUTSZ / 4;  // 186624
  const int i = blockIdx.x * 256 + threadIdx.x;
  if (i >= n4) return;
  float4 s = make_float4(0.f, 0.f, 0.f, 0.f);
  #pragma unroll
  for (int cz = 0; cz < CSPLIT; ++cz) {
    const float4 v = ((const float4*)part)[(size_t)cz * n4 + i];
    s.x += v.x; s.y += v.y; s.z += v.z; s.w += v.w;
  }
  const float sc = 1.f / (float)NC;
  s.x *= sc; s.y *= sc; s.z *= sc; s.w *= sc;
  ((float4*)out)[i] = s;
}

extern "C" void kernel_launch(void* const* d_in, const int* in_sizes, int n_in,
                              void* d_out, int out_size, void* d_ws, size_t ws_size,
                              hipStream_t stream) {
  const float* x1 = (const float*)d_in[0];
  const float* x2 = (const float*)d_in[1];
  float* out = (float*)d_out;

  const size_t need = (size_t)CSPLIT * OUTSZ * sizeof(float);
  const dim3 grid(12, 16, CSPLIT);   // (h1t*2 + whalf, b, cz)
  if (ws_size >= need) {
    float* part = (float*)d_ws;
    corr_main<0><<<grid, 128, 0, stream>>>(x1, x2, part);
    corr_reduce<<<(OUTSZ / 4 + 255) / 256, 256, 0, stream>>>(part, out);
  } else {
    hipMemsetAsync(d_out, 0, (size_t)OUTSZ * sizeof(float), stream);
    corr_main<1><<<grid, 128, 0, stream>>>(x1, x2, out);
  }
}